// Round 1
// baseline (226.501 us; speedup 1.0000x reference)
//
#include <hip/hip_runtime.h>

typedef _Float16 half8 __attribute__((ext_vector_type(8)));
typedef _Float16 half4_t __attribute__((ext_vector_type(4)));
typedef float f32x4 __attribute__((ext_vector_type(4)));

#define NBATCH 2048
#define NA 64
#define SA 128
#define HID 256

// LDS strides in halves (pad +8 -> 16B-aligned rows, 2-way bank aliasing only)
#define LDB 264
#define LDT 72

#define OFF_A 0
#define OFF_B (64 * LDB)             // 16896
#define OFF_ATT (OFF_B + 256 * LDT)  // 35328
#define SMEM_HALVES (OFF_ATT + 64 * LDT)  // 39936 halves = 79872 B

// packed fp16 weight offsets (halves) inside d_ws
#define W_ENC1 0
#define W_ENC2 (W_ENC1 + 128 * 256)
#define W_ATTN (W_ENC2 + 256 * 256)
#define W_GC1 (W_ATTN + 256 * 256)
#define W_NN1 (W_GC1 + 128 * 256)
#define W_GC2 (W_NN1 + 128 * 256)
#define W_NN2 (W_GC2 + 256 * 256)

#define MFMA(a, b, cacc) __builtin_amdgcn_mfma_f32_16x16x32_f16((a), (b), (cacc), 0, 0, 0)

// Pack W[K][256] (f32) into MFMA B-fragment order, fp16:
// dst[((kt*16+nt)*64+lane)*8 + j] = W[kt*32 + (lane>>4)*8 + j][nt*16 + (lane&15)]
__global__ void pack_w_kernel(const float* __restrict__ src, _Float16* __restrict__ dst, int K) {
  int t = blockIdx.x * blockDim.x + threadIdx.x;
  if (t >= K * 32) return;  // (K/32)*16*64 threads
  int lane = t & 63;
  int frag = t >> 6;
  int nt = frag & 15;
  int kt = frag >> 4;
  int g = lane >> 4, c = lane & 15;
  int kb = kt * 32 + g * 8;
  int col = nt * 16 + c;
  half8 h;
#pragma unroll
  for (int j = 0; j < 8; ++j) h[j] = (_Float16)src[(size_t)(kb + j) * 256 + col];
  *(half8*)(dst + (size_t)t * 8) = h;
}

__global__ __launch_bounds__(256, 2) void dicg_main(
    const float* __restrict__ x, const float* __restrict__ b_enc1,
    const float* __restrict__ b_enc2, const float* __restrict__ b_gc1,
    const float* __restrict__ b_nn1, const float* __restrict__ b_gc2,
    const float* __restrict__ b_nn2, const _Float16* __restrict__ wp,
    float* __restrict__ out, float* __restrict__ attn_out) {
  extern __shared__ char smraw[];
  _Float16* sm = (_Float16*)smraw;
  _Float16* A = sm + OFF_A;    // h1 -> q -> feat      [64][LDB]
  _Float16* B = sm + OFF_B;    // emb [64][LDB] -> xg1T/fg2T [256][LDT]
  _Float16* ATT = sm + OFF_ATT;  // attn fp16 [64][LDT]

  const int tid = (int)threadIdx.x;
  const int wv = tid >> 6;       // wave 0..3 (owns cols 64*wv..64*wv+63)
  const int lane = tid & 63;
  const int g = lane >> 4;       // 0..3
  const int c = lane & 15;       // 0..15
  const int bb = (int)blockIdx.x;
  const float* __restrict__ xb = x + (size_t)bb * (NA * SA);

  // A-fragment from LDS row-major: lane holds M[r0+c][k0 + g*8 .. +7]
  auto ldsfrag = [&](const _Float16* p, int ld, int r0, int k0) -> half8 {
    return *(const half8*)(p + (r0 + c) * ld + k0 + g * 8);
  };
  // A-fragment of x straight from global f32
  auto xfrag = [&](int r0, int k0) -> half8 {
    const float* p = xb + (r0 + c) * SA + k0 + g * 8;
    f32x4 u = *(const f32x4*)p;
    f32x4 v = *(const f32x4*)(p + 4);
    half8 h;
    h[0] = (_Float16)u[0]; h[1] = (_Float16)u[1];
    h[2] = (_Float16)u[2]; h[3] = (_Float16)u[3];
    h[4] = (_Float16)v[0]; h[5] = (_Float16)v[1];
    h[6] = (_Float16)v[2]; h[7] = (_Float16)v[3];
    return h;
  };
  // B-fragment from packed weights (one coalesced 16B load)
  auto wfrag = [&](const _Float16* wb, int kt, int ntg) -> half8 {
    return *(const half8*)(wb + ((size_t)(kt * 16 + ntg) * 64 + lane) * 8);
  };

  auto mm_lds = [&](f32x4(&acc)[4][4], const _Float16* Ap, const _Float16* wb, int nkt) {
    for (int kt = 0; kt < nkt; ++kt) {
      half8 af[4], bf[4];
#pragma unroll
      for (int rt = 0; rt < 4; ++rt) af[rt] = ldsfrag(Ap, LDB, 16 * rt, kt * 32);
#pragma unroll
      for (int nt = 0; nt < 4; ++nt) bf[nt] = wfrag(wb, kt, 4 * wv + nt);
#pragma unroll
      for (int rt = 0; rt < 4; ++rt)
#pragma unroll
        for (int nt = 0; nt < 4; ++nt) acc[rt][nt] = MFMA(af[rt], bf[nt], acc[rt][nt]);
    }
  };
  auto mm_x = [&](f32x4(&acc)[4][4], const _Float16* wb, int nkt) {
    for (int kt = 0; kt < nkt; ++kt) {
      half8 af[4], bf[4];
#pragma unroll
      for (int rt = 0; rt < 4; ++rt) af[rt] = xfrag(16 * rt, kt * 32);
#pragma unroll
      for (int nt = 0; nt < 4; ++nt) bf[nt] = wfrag(wb, kt, 4 * wv + nt);
#pragma unroll
      for (int rt = 0; rt < 4; ++rt)
#pragma unroll
        for (int nt = 0; nt < 4; ++nt) acc[rt][nt] = MFMA(af[rt], bf[nt], acc[rt][nt]);
    }
  };
  // attn @ M via transposed-LDS B (K=64): B[k][n] = Mt[n][k]
  auto mm_att = [&](f32x4(&acc)[4][4], const _Float16* Bt) {
#pragma unroll
    for (int kt = 0; kt < 2; ++kt) {
      half8 af[4], bf[4];
#pragma unroll
      for (int rt = 0; rt < 4; ++rt) af[rt] = ldsfrag(ATT, LDT, 16 * rt, kt * 32);
#pragma unroll
      for (int nt = 0; nt < 4; ++nt) bf[nt] = ldsfrag(Bt, LDT, 16 * (4 * wv + nt), kt * 32);
#pragma unroll
      for (int rt = 0; rt < 4; ++rt)
#pragma unroll
        for (int nt = 0; nt < 4; ++nt) acc[rt][nt] = MFMA(af[rt], bf[nt], acc[rt][nt]);
    }
  };
  // D layout: row = 16*rt + 4*g + r, col = 64*wv + 16*nt + c
  auto ep_row = [&](f32x4(&acc)[4][4], _Float16* dst, const float* bias, bool dorelu) {
#pragma unroll
    for (int nt = 0; nt < 4; ++nt) {
      int col = 64 * wv + 16 * nt + c;
      float bv = bias ? bias[col] : 0.f;
#pragma unroll
      for (int rt = 0; rt < 4; ++rt)
#pragma unroll
        for (int r = 0; r < 4; ++r) {
          float y = acc[rt][nt][r] + bv;
          if (dorelu) y = fmaxf(y, 0.f);
          dst[(16 * rt + 4 * g + r) * LDB + col] = (_Float16)y;
        }
    }
  };
  auto ep_tr = [&](f32x4(&acc)[4][4], _Float16* dst, const float* bias) {
#pragma unroll
    for (int nt = 0; nt < 4; ++nt) {
      int col = 64 * wv + 16 * nt + c;
      float bv = bias[col];
#pragma unroll
      for (int rt = 0; rt < 4; ++rt) {
        half4_t h;
#pragma unroll
        for (int r = 0; r < 4; ++r) h[r] = (_Float16)(acc[rt][nt][r] + bv);
        *(half4_t*)(dst + col * LDT + 16 * rt + 4 * g) = h;  // 4 consecutive rows, 8B store
      }
    }
  };
  auto ep_combine = [&](f32x4(&a1)[4][4], f32x4(&a2)[4][4], const float* bias,
                        _Float16* dstLds, float* dstGlob) {
#pragma unroll
    for (int nt = 0; nt < 4; ++nt) {
      int col = 64 * wv + 16 * nt + c;
      float bv = bias[col];
#pragma unroll
      for (int rt = 0; rt < 4; ++rt)
#pragma unroll
        for (int r = 0; r < 4; ++r) {
          float v = (fmaxf(a1[rt][nt][r], 0.f) + fmaxf(a2[rt][nt][r] + bv, 0.f)) * 0.015625f;
          if (dstLds)
            dstLds[(16 * rt + 4 * g + r) * LDB + col] = (_Float16)v;
          else
            dstGlob[((size_t)bb * NA + 16 * rt + 4 * g + r) * HID + col] = v;
        }
    }
  };

  // P1: h1 = relu(x @ enc_w1 + b1) -> A
  {
    f32x4 acc[4][4]{};
    mm_x(acc, wp + W_ENC1, 4);
    ep_row(acc, A, b_enc1, true);
  }
  __syncthreads();
  // P2: emb = relu(h1 @ enc_w2 + b2) -> B
  {
    f32x4 acc[4][4]{};
    mm_lds(acc, A, wp + W_ENC2, 8);
    ep_row(acc, B, b_enc2, true);
  }
  __syncthreads();
  // P3: q = emb @ attn_w -> A
  {
    f32x4 acc[4][4]{};
    mm_lds(acc, B, wp + W_ATTN, 8);
    ep_row(acc, A, nullptr, false);
  }
  __syncthreads();
  // P4: scores = q @ emb^T (row-split: wave wv owns rows 16wv..16wv+15), softmax
  {
    f32x4 sc[4]{};
    for (int kt = 0; kt < 8; ++kt) {
      half8 aq = ldsfrag(A, LDB, 16 * wv, kt * 32);
#pragma unroll
      for (int nt = 0; nt < 4; ++nt) {
        // B[k][m] = emb[m][k] -> A-style read of emb rows 16*nt..+15
        half8 be = ldsfrag(B, LDB, 16 * nt, kt * 32);
        sc[nt] = MFMA(aq, be, sc[nt]);
      }
    }
#pragma unroll
    for (int r = 0; r < 4; ++r) {
      int row = 16 * wv + 4 * g + r;
      float m = fmaxf(fmaxf(sc[0][r], sc[1][r]), fmaxf(sc[2][r], sc[3][r]));
#pragma unroll
      for (int off = 1; off < 16; off <<= 1) m = fmaxf(m, __shfl_xor(m, off, 64));
      float e0 = __expf(sc[0][r] - m), e1 = __expf(sc[1][r] - m);
      float e2 = __expf(sc[2][r] - m), e3 = __expf(sc[3][r] - m);
      float s = e0 + e1 + e2 + e3;
#pragma unroll
      for (int off = 1; off < 16; off <<= 1) s += __shfl_xor(s, off, 64);
      float inv = 1.0f / s;
      float a0 = e0 * inv, a1v = e1 * inv, a2v = e2 * inv, a3v = e3 * inv;
      float* ao = attn_out + ((size_t)bb * NA + row) * NA;
      ao[0 + c] = a0; ao[16 + c] = a1v; ao[32 + c] = a2v; ao[48 + c] = a3v;
      ATT[row * LDT + 0 + c] = (_Float16)a0;
      ATT[row * LDT + 16 + c] = (_Float16)a1v;
      ATT[row * LDT + 32 + c] = (_Float16)a2v;
      ATT[row * LDT + 48 + c] = (_Float16)a3v;
    }
  }
  __syncthreads();
  // P5: xg1 = x @ gc1_w + b (no relu) -> B transposed [256][LDT]
  {
    f32x4 acc[4][4]{};
    mm_x(acc, wp + W_GC1, 4);
    ep_tr(acc, B, b_gc1);
  }
  __syncthreads();
  // P6: feat = (relu(attn @ xg1) + relu(x @ nn1_w + b)) / 64 -> A
  {
    f32x4 a1[4][4]{};
    mm_att(a1, B);
    f32x4 a2[4][4]{};
    mm_x(a2, wp + W_NN1, 4);
    ep_combine(a1, a2, b_nn1, A, nullptr);
  }
  __syncthreads();
  // P7: fg2 = feat @ gc2_w + b (no relu) -> B transposed
  {
    f32x4 acc[4][4]{};
    mm_lds(acc, A, wp + W_GC2, 8);
    ep_tr(acc, B, b_gc2);
  }
  __syncthreads();
  // P8: out = (relu(attn @ fg2) + relu(feat @ nn2_w + b)) / 64 -> global
  {
    f32x4 a1[4][4]{};
    mm_att(a1, B);
    f32x4 a2[4][4]{};
    mm_lds(a2, A, wp + W_NN2, 8);
    ep_combine(a1, a2, b_nn2, nullptr, out);
  }
}

extern "C" void kernel_launch(void* const* d_in, const int* in_sizes, int n_in,
                              void* d_out, int out_size, void* d_ws, size_t ws_size,
                              hipStream_t stream) {
  const float* x = (const float*)d_in[0];
  const float* enc_w1 = (const float*)d_in[1];
  const float* enc_b1 = (const float*)d_in[2];
  const float* enc_w2 = (const float*)d_in[3];
  const float* enc_b2 = (const float*)d_in[4];
  const float* attn_w = (const float*)d_in[5];
  const float* gc1_w = (const float*)d_in[6];
  const float* gc1_b = (const float*)d_in[7];
  const float* nn1_w = (const float*)d_in[8];
  const float* nn1_b = (const float*)d_in[9];
  const float* gc2_w = (const float*)d_in[10];
  const float* gc2_b = (const float*)d_in[11];
  const float* nn2_w = (const float*)d_in[12];
  const float* nn2_b = (const float*)d_in[13];
  // d_in[14] = n_agents (=64, baked in as compile-time constant)

  _Float16* wp = (_Float16*)d_ws;
  float* out = (float*)d_out;
  float* attn_o = out + (size_t)NBATCH * NA * HID;

  pack_w_kernel<<<16, 256, 0, stream>>>(enc_w1, wp + W_ENC1, 128);
  pack_w_kernel<<<32, 256, 0, stream>>>(enc_w2, wp + W_ENC2, 256);
  pack_w_kernel<<<32, 256, 0, stream>>>(attn_w, wp + W_ATTN, 256);
  pack_w_kernel<<<16, 256, 0, stream>>>(gc1_w, wp + W_GC1, 128);
  pack_w_kernel<<<16, 256, 0, stream>>>(nn1_w, wp + W_NN1, 128);
  pack_w_kernel<<<32, 256, 0, stream>>>(gc2_w, wp + W_GC2, 256);
  pack_w_kernel<<<32, 256, 0, stream>>>(nn2_w, wp + W_NN2, 256);

  dicg_main<<<NBATCH, 256, SMEM_HALVES * 2, stream>>>(
      x, enc_b1, enc_b2, gc1_b, nn1_b, gc2_b, nn2_b, wp, out, attn_o);
}